// Round 3
// baseline (1134.416 us; speedup 1.0000x reference)
//
#include <hip/hip_runtime.h>
#include <hip/hip_bf16.h>

typedef __bf16 bf16_t;
typedef bf16_t bf16x8 __attribute__((ext_vector_type(8)));
typedef float f32x16 __attribute__((ext_vector_type(16)));

#define MFMA32(a, b, c) __builtin_amdgcn_mfma_f32_32x32x16_bf16(a, b, c, 0, 0, 0)

static constexpr int E_EDGE = 786432;
static constexpr int N_GRID = 262144;
static constexpr int DIM = 128;

// LDS geometry (bytes)
static constexpr int LDT = 72;                 // padded K-tile row, elems (64+8) -> 144B, 16B aligned, 9 slots
static constexpr int TILE_B = 256 * LDT * 2;   // 36864 B per 256x64 bf16 tile
static constexpr int LDH = 264;                // h row elems (256+8) -> 528B, 33 slots
static constexpr int LDO = 132;                // out row f32 elems -> 528B
static constexpr int OFF_SIDX = 4 * TILE_B;    // 147456
static constexpr int OFF_DIDX = OFF_SIDX + 1024;
static constexpr int SMEM_SZ = OFF_DIDX + 1024;  // 149504 <= 163840

// out[n*K + k] = (bf16) in[k*N + n]   (transpose KxN -> NxK, fp32 -> bf16)
__global__ void transpose_to_bf16(const float* __restrict__ in, bf16_t* __restrict__ out,
                                  int K, int N) {
    int idx = blockIdx.x * 256 + threadIdx.x;
    if (idx < K * N) {
        int n = idx / K;
        int k = idx - n * K;
        out[idx] = (bf16_t)in[k * N + n];
    }
}

// Fused MLP: cat(...) [K1] -> 256 (SiLU) -> 128 (LN) -> scatter/store.
// BM=256 rows/block, 512 threads (8 waves as 2M x 4N), per-wave 128x64 out (GEMM1).
template <bool EDGE>
__global__ __launch_bounds__(512, 2) void mlp_kernel(
    const float* feat0,                 // EDGE: m2g_efeat ; NODE: agg (= out)
    const float* __restrict__ gridf,
    const float* __restrict__ meshf,    // EDGE only
    const int* __restrict__ src_idx,    // EDGE only
    const int* __restrict__ dst_idx,    // EDGE only
    const bf16_t* __restrict__ W1T,     // [256][K1]
    const float* __restrict__ b1,
    const bf16_t* __restrict__ W2T,     // [128][256]
    const float* __restrict__ b2,
    const float* __restrict__ g, const float* __restrict__ beta,
    float* outp)                        // EDGE: agg (atomic) ; NODE: out
{
    __shared__ __align__(16) char smem[SMEM_SZ];

    constexpr int K1 = EDGE ? 384 : 256;
    constexpr int NSTEP = K1 / 64;

    const int tid = threadIdx.x;
    const int wave = tid >> 6, lane = tid & 63;
    const int l31 = lane & 31, lk = lane >> 5;
    const int wm = wave >> 2, wn = wave & 3;
    const int r0 = blockIdx.x * 256;

    int* sidx = (int*)(smem + OFF_SIDX);
    int* didx = (int*)(smem + OFF_DIDX);
    if (EDGE) {
        if (tid < 256) sidx[tid] = src_idx[r0 + tid];
        else didx[tid - 256] = dst_idx[r0 + tid - 256];
        __syncthreads();
    }

    // ---------------- GEMM1: [256, K1] x [K1, 256], dbuf LDS, 1 barrier / K64-step
    const int srow = tid >> 1;        // staging row / weight n-row (0..255)
    const int shalf = tid & 1;        // which 32-col half of the 64-wide K-slice

    float4 aR[8];
    uint4 bR[4];

    auto LOADA = [&](int step) {
        const int kglob = step * 64 + shalf * 32;
        const int seg = kglob >> 7, kin = kglob & 127;
        const float* base;
        if (EDGE) {
            base = (seg == 0) ? feat0 + (size_t)(r0 + srow) * 128 + kin
                 : (seg == 1) ? meshf + (size_t)sidx[srow] * 128 + kin
                              : gridf + (size_t)didx[srow] * 128 + kin;
        } else {
            base = (seg == 0) ? feat0 + (size_t)(r0 + srow) * 128 + kin
                              : gridf + (size_t)(r0 + srow) * 128 + kin;
        }
#pragma unroll
        for (int j = 0; j < 8; ++j)
            aR[j] = *reinterpret_cast<const float4*>(base + j * 4);
    };
    auto LOADB = [&](int step) {
        const uint4* p = reinterpret_cast<const uint4*>(
            W1T + (size_t)srow * K1 + step * 64 + shalf * 32);
#pragma unroll
        for (int j = 0; j < 4; ++j) bR[j] = p[j];
    };
    auto WRITEA = [&](int p) {
        bf16_t* dst = (bf16_t*)(smem + p * (2 * TILE_B)) + srow * LDT + shalf * 32;
#pragma unroll
        for (int q = 0; q < 4; ++q) {
            union { bf16_t h[8]; uint4 u; } pk;
            const float4 v0 = aR[q * 2], v1 = aR[q * 2 + 1];
            pk.h[0] = (bf16_t)v0.x; pk.h[1] = (bf16_t)v0.y;
            pk.h[2] = (bf16_t)v0.z; pk.h[3] = (bf16_t)v0.w;
            pk.h[4] = (bf16_t)v1.x; pk.h[5] = (bf16_t)v1.y;
            pk.h[6] = (bf16_t)v1.z; pk.h[7] = (bf16_t)v1.w;
            *reinterpret_cast<uint4*>(dst + q * 8) = pk.u;
        }
    };
    auto WRITEB = [&](int p) {
        bf16_t* dst = (bf16_t*)(smem + p * (2 * TILE_B) + TILE_B) + srow * LDT + shalf * 32;
#pragma unroll
        for (int j = 0; j < 4; ++j)
            reinterpret_cast<uint4*>(dst)[j] = bR[j];
    };

    f32x16 acc[4][2] = {};
    auto COMPUTE1 = [&](int p) {
        const bf16_t* A = (const bf16_t*)(smem + p * (2 * TILE_B));
        const bf16_t* B = (const bf16_t*)(smem + p * (2 * TILE_B) + TILE_B);
#pragma unroll
        for (int ks = 0; ks < 4; ++ks) {
            const int kb = ks * 16 + lk * 8;
            bf16x8 a[4], b[2];
#pragma unroll
            for (int mt = 0; mt < 4; ++mt)
                a[mt] = *reinterpret_cast<const bf16x8*>(A + (wm * 128 + mt * 32 + l31) * LDT + kb);
#pragma unroll
            for (int nt = 0; nt < 2; ++nt)
                b[nt] = *reinterpret_cast<const bf16x8*>(B + (wn * 64 + nt * 32 + l31) * LDT + kb);
#pragma unroll
            for (int mt = 0; mt < 4; ++mt)
#pragma unroll
                for (int nt = 0; nt < 2; ++nt)
                    acc[mt][nt] = MFMA32(a[mt], b[nt], acc[mt][nt]);
        }
    };

    LOADA(0); LOADB(0);
    WRITEA(0); WRITEB(0);
    __syncthreads();
#pragma unroll
    for (int t = 0; t < NSTEP; ++t) {
        if (t < NSTEP - 1) { LOADA(t + 1); LOADB(t + 1); }
        COMPUTE1(t & 1);
        if (t < NSTEP - 1) {
            WRITEA((t + 1) & 1); WRITEB((t + 1) & 1);
            __syncthreads();
        }
    }
    __syncthreads();  // all GEMM1 LDS reads done before h overwrites the dbuf region

    // ---------------- bias + SiLU -> h [256][LDH] bf16 (overlaps dbuf region)
    bf16_t* hT = (bf16_t*)smem;
#pragma unroll
    for (int nt = 0; nt < 2; ++nt) {
        const int col = wn * 64 + nt * 32 + l31;
        const float bb = b1[col];
#pragma unroll
        for (int mt = 0; mt < 4; ++mt) {
#pragma unroll
            for (int r = 0; r < 16; ++r) {
                const int row = wm * 128 + mt * 32 + (r & 3) + 8 * (r >> 2) + 4 * lk;
                const float x = acc[mt][nt][r] + bb;
                hT[row * LDH + col] = (bf16_t)(x / (1.f + __expf(-x)));
            }
        }
    }
    __syncthreads();

    // ---------------- GEMM2: [256,256] x [256,128]; B fully in registers, no barriers
    bf16x8 bf2[16];
#pragma unroll
    for (int ksub = 0; ksub < 16; ++ksub)
        bf2[ksub] = *reinterpret_cast<const bf16x8*>(
            W2T + (size_t)(wn * 32 + l31) * 256 + ksub * 16 + lk * 8);

    f32x16 acc2[4] = {};
#pragma unroll
    for (int ksub = 0; ksub < 16; ++ksub) {
        const int kb = ksub * 16 + lk * 8;
        bf16x8 a[4];
#pragma unroll
        for (int mt = 0; mt < 4; ++mt)
            a[mt] = *reinterpret_cast<const bf16x8*>(hT + (wm * 128 + mt * 32 + l31) * LDH + kb);
#pragma unroll
        for (int mt = 0; mt < 4; ++mt)
            acc2[mt] = MFMA32(a[mt], bf2[ksub], acc2[mt]);
    }
    __syncthreads();  // all h reads done before outl overwrites it

    // ---------------- bias -> outl [256][LDO] f32 (overlaps h)
    float* outl = (float*)smem;
    {
        const int col = wn * 32 + l31;
        const float bb = b2[col];
#pragma unroll
        for (int mt = 0; mt < 4; ++mt)
#pragma unroll
            for (int r = 0; r < 16; ++r) {
                const int row = wm * 128 + mt * 32 + (r & 3) + 8 * (r >> 2) + 4 * lk;
                outl[row * LDO + col] = acc2[mt][r] + bb;
            }
    }
    __syncthreads();

    // ---------------- LayerNorm: 2 threads per row
    {
        const int lrow = tid >> 1, lhalf = tid & 1;
        const float* rp = outl + lrow * LDO + lhalf * 64;
        float s = 0.f, sq = 0.f;
#pragma unroll
        for (int q = 0; q < 16; ++q) {
            const float4 v = *reinterpret_cast<const float4*>(rp + q * 4);
            s += v.x + v.y + v.z + v.w;
            sq += v.x * v.x + v.y * v.y + v.z * v.z + v.w * v.w;
        }
        s += __shfl_xor(s, 1);
        sq += __shfl_xor(sq, 1);
        const float mean = s * (1.f / 128.f);
        const float var = sq * (1.f / 128.f) - mean * mean;
        const float rstd = rsqrtf(var + 1e-5f);

        if (EDGE) {
            float* wp = outl + lrow * LDO + lhalf * 64;
#pragma unroll
            for (int q = 0; q < 16; ++q) {
                const float4 v = *reinterpret_cast<const float4*>(rp + q * 4);
                const float4 gv = *reinterpret_cast<const float4*>(g + lhalf * 64 + q * 4);
                const float4 bv = *reinterpret_cast<const float4*>(beta + lhalf * 64 + q * 4);
                float4 y;
                y.x = (v.x - mean) * rstd * gv.x + bv.x;
                y.y = (v.y - mean) * rstd * gv.y + bv.y;
                y.z = (v.z - mean) * rstd * gv.z + bv.z;
                y.w = (v.w - mean) * rstd * gv.w + bv.w;
                *reinterpret_cast<float4*>(wp + q * 4) = y;
            }
        } else {
            const float* grp = gridf + (size_t)(r0 + lrow) * 128 + lhalf * 64;
            float* op = outp + (size_t)(r0 + lrow) * 128 + lhalf * 64;
#pragma unroll
            for (int q = 0; q < 16; ++q) {
                const float4 v = *reinterpret_cast<const float4*>(rp + q * 4);
                const float4 gv = *reinterpret_cast<const float4*>(g + lhalf * 64 + q * 4);
                const float4 bv = *reinterpret_cast<const float4*>(beta + lhalf * 64 + q * 4);
                const float4 rr = *reinterpret_cast<const float4*>(grp + q * 4);
                float4 y;
                y.x = (v.x - mean) * rstd * gv.x + bv.x + rr.x;
                y.y = (v.y - mean) * rstd * gv.y + bv.y + rr.y;
                y.z = (v.z - mean) * rstd * gv.z + bv.z + rr.z;
                y.w = (v.w - mean) * rstd * gv.w + bv.w + rr.w;
                *reinterpret_cast<float4*>(op + q * 4) = y;
            }
        }
    }

    if (EDGE) {
        __syncthreads();
        // coalesced atomic scatter: each wave scatters 32 rows, lane-consecutive
        for (int r = 0; r < 32; ++r) {
            const int row = wave * 32 + r;
            const int dst = didx[row];
            float* ap = outp + (size_t)dst * 128;
            atomicAdd(ap + lane, outl[row * LDO + lane]);
            atomicAdd(ap + 64 + lane, outl[row * LDO + 64 + lane]);
        }
    }
}

extern "C" void kernel_launch(void* const* d_in, const int* in_sizes, int n_in,
                              void* d_out, int out_size, void* d_ws, size_t ws_size,
                              hipStream_t stream) {
    const float* m2g = (const float*)d_in[0];
    const float* gridf = (const float*)d_in[1];
    const float* meshf = (const float*)d_in[2];
    const int* src_idx = (const int*)d_in[3];
    const int* dst_idx = (const int*)d_in[4];
    const float* eW1 = (const float*)d_in[5];
    const float* eb1 = (const float*)d_in[6];
    const float* eW2 = (const float*)d_in[7];
    const float* eb2 = (const float*)d_in[8];
    const float* eg = (const float*)d_in[9];
    const float* ebeta = (const float*)d_in[10];
    const float* nW1 = (const float*)d_in[11];
    const float* nb1 = (const float*)d_in[12];
    const float* nW2 = (const float*)d_in[13];
    const float* nb2 = (const float*)d_in[14];
    const float* ng = (const float*)d_in[15];
    const float* nbeta = (const float*)d_in[16];
    float* out = (float*)d_out;

    bf16_t* W1eT = (bf16_t*)d_ws;          // [256][384]
    bf16_t* W2eT = W1eT + 256 * 384;       // [128][256]
    bf16_t* W1nT = W2eT + 128 * 256;       // [256][256]
    bf16_t* W2nT = W1nT + 256 * 256;       // [128][256]

    // agg lives in d_out; zero it first (edge kernel atomically accumulates into it)
    hipMemsetAsync(d_out, 0, (size_t)N_GRID * DIM * sizeof(float), stream);

    transpose_to_bf16<<<(384 * 256 + 255) / 256, 256, 0, stream>>>(eW1, W1eT, 384, 256);
    transpose_to_bf16<<<(256 * 128 + 255) / 256, 256, 0, stream>>>(eW2, W2eT, 256, 128);
    transpose_to_bf16<<<(256 * 256 + 255) / 256, 256, 0, stream>>>(nW1, W1nT, 256, 256);
    transpose_to_bf16<<<(256 * 128 + 255) / 256, 256, 0, stream>>>(nW2, W2nT, 256, 128);

    mlp_kernel<true><<<E_EDGE / 256, 512, 0, stream>>>(
        m2g, gridf, meshf, src_idx, dst_idx,
        W1eT, eb1, W2eT, eb2, eg, ebeta, out);
    mlp_kernel<false><<<N_GRID / 256, 512, 0, stream>>>(
        out, gridf, nullptr, nullptr, nullptr,
        W1nT, nb1, W2nT, nb2, ng, nbeta, out);
}

// Round 5
// 884.388 us; speedup vs baseline: 1.2827x; 1.2827x over previous
//
#include <hip/hip_runtime.h>
#include <hip/hip_bf16.h>

typedef __bf16 bf16_t;
typedef bf16_t bf16x8 __attribute__((ext_vector_type(8)));
typedef float f32x16 __attribute__((ext_vector_type(16)));

#define MFMA32(a, b, c) __builtin_amdgcn_mfma_f32_32x32x16_bf16(a, b, c, 0, 0, 0)

static constexpr int E_EDGE = 786432;
static constexpr int N_GRID = 262144;

// LDS geometry
static constexpr int LDT = 72;                  // A-tile row elems (64+8)
static constexpr int ATB = 128 * LDT * 2;       // 18432 B per A tile
static constexpr int LDH = 264;                 // h row elems (256+8)
static constexpr int LDO = 132;                 // out row f32 elems
static constexpr int HB = 128 * LDH * 2;        // 67584 B (== 128*LDO*4)
static constexpr int OFF_SIDX = HB;             // 67584
static constexpr int OFF_DIDX = OFF_SIDX + 512;
static constexpr int SMEM_SZ = OFF_DIDX + 512;  // 68608 B -> 2 blocks/CU

// out[n*K + k] = (bf16) in[k*N + n]
__global__ void transpose_to_bf16(const float* __restrict__ in, bf16_t* __restrict__ out,
                                  int K, int N) {
    int idx = blockIdx.x * 256 + threadIdx.x;
    if (idx < K * N) {
        int n = idx / K;
        int k = idx - n * K;
        out[idx] = (bf16_t)in[k * N + n];
    }
}

// Fused MLP: cat(...)[K1] -> 256 (SiLU) -> 128 (LN) -> scatter/store.
// BM=128 rows/block, 512 threads (8 waves).
// GEMM1: each wave owns one 32-wide N-slice (wave*32..wave*32+31) over all 128 rows.
// GEMM2: waves as 2M x 4N (wm picks 64-row half, wn picks 32-col slice).
// W1/W2 B-operands read straight from L2 / held in registers; only gathered A staged in LDS.
template <bool EDGE>
__global__ __launch_bounds__(512, 4) void mlp_kernel(
    const float* feat0,                 // EDGE: m2g_efeat ; NODE: agg (= out)
    const float* __restrict__ gridf,
    const float* __restrict__ meshf,    // EDGE only
    const int* __restrict__ src_idx,    // EDGE only
    const int* __restrict__ dst_idx,    // EDGE only
    const bf16_t* __restrict__ W1T,     // [256][K1]
    const float* __restrict__ b1,
    const bf16_t* __restrict__ W2T,     // [128][256]
    const float* __restrict__ b2,
    const float* __restrict__ g, const float* __restrict__ beta,
    float* outp)                        // EDGE: agg (atomic) ; NODE: out
{
    __shared__ __align__(16) char smem[SMEM_SZ];

    constexpr int K1 = EDGE ? 384 : 256;
    constexpr int NSTEP = K1 / 64;

    const int tid = threadIdx.x;
    const int wave = tid >> 6, lane = tid & 63;
    const int l31 = lane & 31, lk = lane >> 5;
    const int wm = wave >> 2, wn = wave & 3;
    const int r0 = blockIdx.x * 128;

    int* sidx = (int*)(smem + OFF_SIDX);
    int* didx = (int*)(smem + OFF_DIDX);
    if (EDGE) {
        if (tid < 128) sidx[tid] = src_idx[r0 + tid];
        else if (tid < 256) didx[tid - 128] = dst_idx[r0 + tid - 128];
        __syncthreads();
    }

    // ---------------- GEMM1: [128,K1] x [K1,256] ----------------
    const int srow = tid >> 2;      // staging row 0..127
    const int sq = (tid & 3) * 16;  // 16-col chunk within K64 step

    float4 aR[4];
    auto LOADA = [&](int step) {
        const int kglob = step * 64 + sq;
        const int seg = kglob >> 7, kin = kglob & 127;
        const float* base;
        if (EDGE) {
            base = (seg == 0) ? feat0 + (size_t)(r0 + srow) * 128 + kin
                 : (seg == 1) ? meshf + (size_t)sidx[srow] * 128 + kin
                              : gridf + (size_t)didx[srow] * 128 + kin;
        } else {
            base = (seg == 0) ? feat0 + (size_t)(r0 + srow) * 128 + kin
                              : gridf + (size_t)(r0 + srow) * 128 + kin;
        }
#pragma unroll
        for (int j = 0; j < 4; ++j)
            aR[j] = *reinterpret_cast<const float4*>(base + j * 4);
    };
    auto WRITEA = [&](int p) {
        bf16_t* dst = (bf16_t*)(smem + p * ATB) + srow * LDT + sq;
#pragma unroll
        for (int q = 0; q < 2; ++q) {
            union { bf16_t h[8]; uint4 u; } pk;
            const float4 v0 = aR[q * 2], v1 = aR[q * 2 + 1];
            pk.h[0] = (bf16_t)v0.x; pk.h[1] = (bf16_t)v0.y;
            pk.h[2] = (bf16_t)v0.z; pk.h[3] = (bf16_t)v0.w;
            pk.h[4] = (bf16_t)v1.x; pk.h[5] = (bf16_t)v1.y;
            pk.h[6] = (bf16_t)v1.z; pk.h[7] = (bf16_t)v1.w;
            *reinterpret_cast<uint4*>(dst + q * 8) = pk.u;
        }
    };

    f32x16 acc[4] = {};
    LOADA(0);
    WRITEA(0);
    __syncthreads();
#pragma unroll
    for (int t = 0; t < NSTEP; ++t) {
        if (t < NSTEP - 1) LOADA(t + 1);
        // b-frags straight from L2: this wave's 32-wide N-slice = rows wave*32.. of W1T
        const bf16_t* wrow = W1T + (size_t)(wave * 32 + l31) * K1 + t * 64 + lk * 8;
        bf16x8 b[4];
#pragma unroll
        for (int ks = 0; ks < 4; ++ks)
            b[ks] = *reinterpret_cast<const bf16x8*>(wrow + ks * 16);
        const bf16_t* A = (const bf16_t*)(smem + (t & 1) * ATB);
#pragma unroll
        for (int ks = 0; ks < 4; ++ks) {
            const int kb = ks * 16 + lk * 8;
            bf16x8 a[4];
#pragma unroll
            for (int mt = 0; mt < 4; ++mt)
                a[mt] = *reinterpret_cast<const bf16x8*>(A + (mt * 32 + l31) * LDT + kb);
#pragma unroll
            for (int mt = 0; mt < 4; ++mt)
                acc[mt] = MFMA32(a[mt], b[ks], acc[mt]);
        }
        if (t < NSTEP - 1) {
            WRITEA((t + 1) & 1);
            __syncthreads();
        }
    }
    __syncthreads();  // last-step A reads done before h overwrites dbuf region

    // ---------------- bias + SiLU -> h [128][LDH] bf16 ----------------
    bf16_t* hT = (bf16_t*)smem;
    {
        const int col = wave * 32 + l31;   // this wave's N-slice (0..255)
        const float bb = b1[col];
#pragma unroll
        for (int mt = 0; mt < 4; ++mt)
#pragma unroll
            for (int r = 0; r < 16; ++r) {
                const int row = mt * 32 + (r & 3) + 8 * (r >> 2) + 4 * lk;
                const float x = acc[mt][r] + bb;
                hT[row * LDH + col] = (bf16_t)(x / (1.f + __expf(-x)));
            }
    }
    __syncthreads();

    // ---------------- GEMM2: [128,256] x [256,128]; W2 in regs, no barriers ----------------
    bf16x8 b2f[16];
#pragma unroll
    for (int ks = 0; ks < 16; ++ks)
        b2f[ks] = *reinterpret_cast<const bf16x8*>(
            W2T + (size_t)(wn * 32 + l31) * 256 + ks * 16 + lk * 8);

    f32x16 acc2[2] = {};
#pragma unroll
    for (int ks = 0; ks < 16; ++ks) {
        const int kb = ks * 16 + lk * 8;
        bf16x8 a[2];
#pragma unroll
        for (int mt = 0; mt < 2; ++mt)
            a[mt] = *reinterpret_cast<const bf16x8*>(hT + (wm * 64 + mt * 32 + l31) * LDH + kb);
#pragma unroll
        for (int mt = 0; mt < 2; ++mt)
            acc2[mt] = MFMA32(a[mt], b2f[ks], acc2[mt]);
    }
    __syncthreads();  // h reads done before outl overwrites it

    // ---------------- bias -> outl [128][LDO] f32 ----------------
    float* outl = (float*)smem;
    {
        const int col = wn * 32 + l31;
        const float bb = b2[col];
#pragma unroll
        for (int mt = 0; mt < 2; ++mt)
#pragma unroll
            for (int r = 0; r < 16; ++r) {
                const int row = wm * 64 + mt * 32 + (r & 3) + 8 * (r >> 2) + 4 * lk;
                outl[row * LDO + col] = acc2[mt][r] + bb;
            }
    }
    __syncthreads();

    // ---------------- LayerNorm: 4 threads per row ----------------
    {
        const int lrow = tid >> 2, lq = (tid & 3) * 32;
        const float* rp = outl + lrow * LDO + lq;
        float s = 0.f, sq2 = 0.f;
#pragma unroll
        for (int q = 0; q < 8; ++q) {
            const float4 v = *reinterpret_cast<const float4*>(rp + q * 4);
            s += v.x + v.y + v.z + v.w;
            sq2 += v.x * v.x + v.y * v.y + v.z * v.z + v.w * v.w;
        }
        s += __shfl_xor(s, 1);  sq2 += __shfl_xor(sq2, 1);
        s += __shfl_xor(s, 2);  sq2 += __shfl_xor(sq2, 2);
        const float mean = s * (1.f / 128.f);
        const float var = sq2 * (1.f / 128.f) - mean * mean;
        const float rstd = rsqrtf(var + 1e-5f);

        if (EDGE) {
            float* wp = outl + lrow * LDO + lq;
#pragma unroll
            for (int q = 0; q < 8; ++q) {
                const float4 v = *reinterpret_cast<const float4*>(rp + q * 4);
                const float4 gv = *reinterpret_cast<const float4*>(g + lq + q * 4);
                const float4 bv = *reinterpret_cast<const float4*>(beta + lq + q * 4);
                float4 y;
                y.x = (v.x - mean) * rstd * gv.x + bv.x;
                y.y = (v.y - mean) * rstd * gv.y + bv.y;
                y.z = (v.z - mean) * rstd * gv.z + bv.z;
                y.w = (v.w - mean) * rstd * gv.w + bv.w;
                *reinterpret_cast<float4*>(wp + q * 4) = y;
            }
        } else {
            const float* grp = gridf + (size_t)(r0 + lrow) * 128 + lq;
            float* op = outp + (size_t)(r0 + lrow) * 128 + lq;
#pragma unroll
            for (int q = 0; q < 8; ++q) {
                const float4 v = *reinterpret_cast<const float4*>(rp + q * 4);
                const float4 gv = *reinterpret_cast<const float4*>(g + lq + q * 4);
                const float4 bv = *reinterpret_cast<const float4*>(beta + lq + q * 4);
                const float4 rr = *reinterpret_cast<const float4*>(grp + q * 4);
                float4 y;
                y.x = (v.x - mean) * rstd * gv.x + bv.x + rr.x;
                y.y = (v.y - mean) * rstd * gv.y + bv.y + rr.y;
                y.z = (v.z - mean) * rstd * gv.z + bv.z + rr.z;
                y.w = (v.w - mean) * rstd * gv.w + bv.w + rr.w;
                *reinterpret_cast<float4*>(op + q * 4) = y;
            }
        }
    }

    if (EDGE) {
        __syncthreads();
        // coalesced atomic scatter: each wave scatters 16 rows, lane-consecutive
#pragma unroll
        for (int r = 0; r < 16; ++r) {
            const int row = wave * 16 + r;
            const int dst = didx[row];
            float* ap = outp + (size_t)dst * 128;
            atomicAdd(ap + lane, outl[row * LDO + lane]);
            atomicAdd(ap + 64 + lane, outl[row * LDO + 64 + lane]);
        }
    }
}

extern "C" void kernel_launch(void* const* d_in, const int* in_sizes, int n_in,
                              void* d_out, int out_size, void* d_ws, size_t ws_size,
                              hipStream_t stream) {
    const float* m2g = (const float*)d_in[0];
    const float* gridf = (const float*)d_in[1];
    const float* meshf = (const float*)d_in[2];
    const int* src_idx = (const int*)d_in[3];
    const int* dst_idx = (const int*)d_in[4];
    const float* eW1 = (const float*)d_in[5];
    const float* eb1 = (const float*)d_in[6];
    const float* eW2 = (const float*)d_in[7];
    const float* eb2 = (const float*)d_in[8];
    const float* eg = (const float*)d_in[9];
    const float* ebeta = (const float*)d_in[10];
    const float* nW1 = (const float*)d_in[11];
    const float* nb1 = (const float*)d_in[12];
    const float* nW2 = (const float*)d_in[13];
    const float* nb2 = (const float*)d_in[14];
    const float* ng = (const float*)d_in[15];
    const float* nbeta = (const float*)d_in[16];
    float* out = (float*)d_out;

    bf16_t* W1eT = (bf16_t*)d_ws;          // [256][384]
    bf16_t* W2eT = W1eT + 256 * 384;       // [128][256]
    bf16_t* W1nT = W2eT + 128 * 256;       // [256][256]
    bf16_t* W2nT = W1nT + 256 * 256;       // [128][256]

    // agg lives in d_out; zero it first (edge kernel atomically accumulates into it)
    hipMemsetAsync(d_out, 0, (size_t)N_GRID * 128 * sizeof(float), stream);

    transpose_to_bf16<<<(384 * 256 + 255) / 256, 256, 0, stream>>>(eW1, W1eT, 384, 256);
    transpose_to_bf16<<<(256 * 128 + 255) / 256, 256, 0, stream>>>(eW2, W2eT, 256, 128);
    transpose_to_bf16<<<(256 * 256 + 255) / 256, 256, 0, stream>>>(nW1, W1nT, 256, 256);
    transpose_to_bf16<<<(256 * 128 + 255) / 256, 256, 0, stream>>>(nW2, W2nT, 256, 128);

    mlp_kernel<true><<<E_EDGE / 128, 512, 0, stream>>>(
        m2g, gridf, meshf, src_idx, dst_idx,
        W1eT, eb1, W2eT, eb2, eg, ebeta, out);
    mlp_kernel<false><<<N_GRID / 128, 512, 0, stream>>>(
        out, gridf, nullptr, nullptr, nullptr,
        W1nT, nb1, W2nT, nb2, ng, nbeta, out);
}

// Round 6
// 824.675 us; speedup vs baseline: 1.3756x; 1.0724x over previous
//
#include <hip/hip_runtime.h>
#include <hip/hip_bf16.h>

typedef __bf16 bf16_t;
typedef bf16_t bf16x8 __attribute__((ext_vector_type(8)));
typedef float f32x16 __attribute__((ext_vector_type(16)));

#define MFMA32(a, b, c) __builtin_amdgcn_mfma_f32_32x32x16_bf16(a, b, c, 0, 0, 0)

static constexpr int E_EDGE = 786432;
static constexpr int N_GRID = 262144;

// LDS geometry
static constexpr int LDT = 72;                  // A-tile row elems (64+8)
static constexpr int ATB = 128 * LDT * 2;       // 18432 B per A tile
static constexpr int LDH = 264;                 // h row elems (256+8)
static constexpr int LDO = 132;                 // out row f32 elems
static constexpr int HB = 128 * LDH * 2;        // 67584 B (== 128*LDO*4)
static constexpr int OFF_SIDX = HB;
static constexpr int OFF_DIDX = OFF_SIDX + 512;
static constexpr int SMEM_SZ = OFF_DIDX + 512;  // 68608 B -> 2 blocks/CU

// out[n*K + k] = (bf16) in[k*N + n]
__global__ void transpose_to_bf16(const float* __restrict__ in, bf16_t* __restrict__ out,
                                  int K, int N) {
    int idx = blockIdx.x * 256 + threadIdx.x;
    if (idx < K * N) {
        int n = idx / K;
        int k = idx - n * K;
        out[idx] = (bf16_t)in[k * N + n];
    }
}

// packed f32 -> bf16 (8 elems/thread)
__global__ void f32_to_bf16_vec(const float* __restrict__ in, bf16_t* __restrict__ out, int n8) {
    int i = blockIdx.x * 256 + threadIdx.x;
    if (i < n8) {
        const float4* p = reinterpret_cast<const float4*>(in + (size_t)i * 8);
        const float4 a = p[0], b = p[1];
        union { bf16_t h[8]; uint4 u; } pk;
        pk.h[0] = (bf16_t)a.x; pk.h[1] = (bf16_t)a.y; pk.h[2] = (bf16_t)a.z; pk.h[3] = (bf16_t)a.w;
        pk.h[4] = (bf16_t)b.x; pk.h[5] = (bf16_t)b.y; pk.h[6] = (bf16_t)b.z; pk.h[7] = (bf16_t)b.w;
        reinterpret_cast<uint4*>(out)[i] = pk.u;
    }
}

// Fused MLP: cat(...)[K1] -> 256 (SiLU) -> 128 (LN) -> scatter/store.
// BM=128 rows/block, 512 threads (8 waves).
// GEMM1: each wave owns one 32-wide N-slice over all 128 rows; B from L2.
// GEMM2: waves 2M x 4N; W2 in registers. Only gathered A staged in LDS (dbuf,
// 2-deep register prefetch). Steps 0-1 stage f32->bf16 (m2g / agg); steps >=2
// stage raw bf16 from pre-converted tables when TBL (numerics identical).
template <bool EDGE, bool TBL>
__global__ __launch_bounds__(512, 4) void mlp_kernel(
    const float* feat0,                 // EDGE: m2g_efeat ; NODE: agg (= out)
    const float* __restrict__ gridf,
    const float* __restrict__ meshf,
    const bf16_t* __restrict__ gridb,   // bf16 tables (TBL only)
    const bf16_t* __restrict__ meshb,
    const int* __restrict__ src_idx,
    const int* __restrict__ dst_idx,
    const bf16_t* __restrict__ W1T,     // [256][K1]
    const float* __restrict__ b1,
    const bf16_t* __restrict__ W2T,     // [128][256]
    const float* __restrict__ b2,
    const float* __restrict__ g, const float* __restrict__ beta,
    float* outp)                        // EDGE: agg (atomic) ; NODE: out
{
    __shared__ __align__(16) char smem[SMEM_SZ];

    constexpr int K1 = EDGE ? 384 : 256;
    constexpr int NSTEP = K1 / 64;

    const int tid = threadIdx.x;
    const int wave = tid >> 6, lane = tid & 63;
    const int l31 = lane & 31, lk = lane >> 5;
    const int wm = wave >> 2, wn = wave & 3;
    const int r0 = blockIdx.x * 128;

    int* sidx = (int*)(smem + OFF_SIDX);
    int* didx = (int*)(smem + OFF_DIDX);
    if (EDGE) {
        if (tid < 128) sidx[tid] = src_idx[r0 + tid];
        else if (tid < 256) didx[tid - 128] = dst_idx[r0 + tid - 128];
        __syncthreads();
    }

    // ---------------- GEMM1: [128,K1] x [K1,256] ----------------
    const int srow = tid >> 2;      // staging row 0..127
    const int sq = (tid & 3) * 16;  // 16-col chunk within K64 step

    union AReg { float4 f[4]; uint4 b[2]; };
    AReg R[2];

    auto LOADA = [&](int step, int set) {
        if (step < 2) {
            // f32 source: EDGE = m2g row, NODE = agg row (cols 0..127)
            const float* base = feat0 + (size_t)(r0 + srow) * 128 + step * 64 + sq;
#pragma unroll
            for (int j = 0; j < 4; ++j)
                R[set].f[j] = *reinterpret_cast<const float4*>(base + j * 4);
        } else if (TBL) {
            const bf16_t* bp;
            if (EDGE)
                bp = (step < 4) ? meshb + (size_t)sidx[srow] * 128 + (step - 2) * 64 + sq
                                : gridb + (size_t)didx[srow] * 128 + (step - 4) * 64 + sq;
            else
                bp = gridb + (size_t)(r0 + srow) * 128 + (step - 2) * 64 + sq;
            R[set].b[0] = *reinterpret_cast<const uint4*>(bp);
            R[set].b[1] = *reinterpret_cast<const uint4*>(bp + 8);
        } else {
            const float* base;
            if (EDGE)
                base = (step < 4) ? meshf + (size_t)sidx[srow] * 128 + (step - 2) * 64 + sq
                                  : gridf + (size_t)didx[srow] * 128 + (step - 4) * 64 + sq;
            else
                base = gridf + (size_t)(r0 + srow) * 128 + (step - 2) * 64 + sq;
#pragma unroll
            for (int j = 0; j < 4; ++j)
                R[set].f[j] = *reinterpret_cast<const float4*>(base + j * 4);
        }
    };
    auto WRITEA = [&](int step, int set, int p) {
        bf16_t* dst = (bf16_t*)(smem + p * ATB) + srow * LDT + sq;
        if (step < 2 || !TBL) {
#pragma unroll
            for (int q = 0; q < 2; ++q) {
                union { bf16_t h[8]; uint4 u; } pk;
                const float4 v0 = R[set].f[q * 2], v1 = R[set].f[q * 2 + 1];
                pk.h[0] = (bf16_t)v0.x; pk.h[1] = (bf16_t)v0.y;
                pk.h[2] = (bf16_t)v0.z; pk.h[3] = (bf16_t)v0.w;
                pk.h[4] = (bf16_t)v1.x; pk.h[5] = (bf16_t)v1.y;
                pk.h[6] = (bf16_t)v1.z; pk.h[7] = (bf16_t)v1.w;
                *reinterpret_cast<uint4*>(dst + q * 8) = pk.u;
            }
        } else {
            *reinterpret_cast<uint4*>(dst) = R[set].b[0];
            *reinterpret_cast<uint4*>(dst + 8) = R[set].b[1];
        }
    };

    f32x16 acc[4] = {};
    LOADA(0, 0);
    LOADA(1, 1);
    WRITEA(0, 0, 0);
    __syncthreads();
#pragma unroll
    for (int t = 0; t < NSTEP; ++t) {
        if (t + 2 < NSTEP) LOADA(t + 2, t & 1);   // 2-deep gather prefetch
        // b-frags from L2: this wave's 32-wide N-slice of W1T
        const bf16_t* wrow = W1T + (size_t)(wave * 32 + l31) * K1 + t * 64 + lk * 8;
        bf16x8 b[4];
#pragma unroll
        for (int ks = 0; ks < 4; ++ks)
            b[ks] = *reinterpret_cast<const bf16x8*>(wrow + ks * 16);
        const bf16_t* A = (const bf16_t*)(smem + (t & 1) * ATB);
#pragma unroll
        for (int ks = 0; ks < 4; ++ks) {
            const int kb = ks * 16 + lk * 8;
            bf16x8 a[4];
#pragma unroll
            for (int mt = 0; mt < 4; ++mt)
                a[mt] = *reinterpret_cast<const bf16x8*>(A + (mt * 32 + l31) * LDT + kb);
#pragma unroll
            for (int mt = 0; mt < 4; ++mt)
                acc[mt] = MFMA32(a[mt], b[ks], acc[mt]);
        }
        if (t + 1 < NSTEP) {
            WRITEA(t + 1, (t + 1) & 1, (t + 1) & 1);
            __syncthreads();
        }
    }
    __syncthreads();  // last-step A reads done before h overwrites dbuf region

    // ---------------- bias + SiLU -> h [128][LDH] bf16 ----------------
    bf16_t* hT = (bf16_t*)smem;
    {
        const int col = wave * 32 + l31;   // this wave's N-slice (0..255)
        const float bb = b1[col];
#pragma unroll
        for (int mt = 0; mt < 4; ++mt)
#pragma unroll
            for (int r = 0; r < 16; ++r) {
                const int row = mt * 32 + (r & 3) + 8 * (r >> 2) + 4 * lk;
                const float x = acc[mt][r] + bb;
                hT[row * LDH + col] = (bf16_t)(x / (1.f + __expf(-x)));
            }
    }
    __syncthreads();

    // ---------------- GEMM2: [128,256] x [256,128]; W2 in regs, no barriers ----------------
    bf16x8 b2f[16];
#pragma unroll
    for (int ks = 0; ks < 16; ++ks)
        b2f[ks] = *reinterpret_cast<const bf16x8*>(
            W2T + (size_t)(wn * 32 + l31) * 256 + ks * 16 + lk * 8);

    f32x16 acc2[2] = {};
#pragma unroll
    for (int ks = 0; ks < 16; ++ks) {
        const int kb = ks * 16 + lk * 8;
        bf16x8 a[2];
#pragma unroll
        for (int mt = 0; mt < 2; ++mt)
            a[mt] = *reinterpret_cast<const bf16x8*>(hT + (wm * 64 + mt * 32 + l31) * LDH + kb);
#pragma unroll
        for (int mt = 0; mt < 2; ++mt)
            acc2[mt] = MFMA32(a[mt], b2f[ks], acc2[mt]);
    }
    __syncthreads();  // h reads done before outl overwrites it

    // ---------------- bias -> outl [128][LDO] f32 ----------------
    float* outl = (float*)smem;
    {
        const int col = wn * 32 + l31;
        const float bb = b2[col];
#pragma unroll
        for (int mt = 0; mt < 2; ++mt)
#pragma unroll
            for (int r = 0; r < 16; ++r) {
                const int row = wm * 64 + mt * 32 + (r & 3) + 8 * (r >> 2) + 4 * lk;
                outl[row * LDO + col] = acc2[mt][r] + bb;
            }
    }
    __syncthreads();

    // ---------------- LayerNorm: 4 threads per row ----------------
    {
        const int lrow = tid >> 2, lq = (tid & 3) * 32;
        const float* rp = outl + lrow * LDO + lq;
        float s = 0.f, sq2 = 0.f;
#pragma unroll
        for (int q = 0; q < 8; ++q) {
            const float4 v = *reinterpret_cast<const float4*>(rp + q * 4);
            s += v.x + v.y + v.z + v.w;
            sq2 += v.x * v.x + v.y * v.y + v.z * v.z + v.w * v.w;
        }
        s += __shfl_xor(s, 1);  sq2 += __shfl_xor(sq2, 1);
        s += __shfl_xor(s, 2);  sq2 += __shfl_xor(sq2, 2);
        const float mean = s * (1.f / 128.f);
        const float var = sq2 * (1.f / 128.f) - mean * mean;
        const float rstd = rsqrtf(var + 1e-5f);

        if (EDGE) {
            float* wp = outl + lrow * LDO + lq;
#pragma unroll
            for (int q = 0; q < 8; ++q) {
                const float4 v = *reinterpret_cast<const float4*>(rp + q * 4);
                const float4 gv = *reinterpret_cast<const float4*>(g + lq + q * 4);
                const float4 bv = *reinterpret_cast<const float4*>(beta + lq + q * 4);
                float4 y;
                y.x = (v.x - mean) * rstd * gv.x + bv.x;
                y.y = (v.y - mean) * rstd * gv.y + bv.y;
                y.z = (v.z - mean) * rstd * gv.z + bv.z;
                y.w = (v.w - mean) * rstd * gv.w + bv.w;
                *reinterpret_cast<float4*>(wp + q * 4) = y;
            }
        } else {
            const float* grp = gridf + (size_t)(r0 + lrow) * 128 + lq;
            float* op = outp + (size_t)(r0 + lrow) * 128 + lq;
#pragma unroll
            for (int q = 0; q < 8; ++q) {
                const float4 v = *reinterpret_cast<const float4*>(rp + q * 4);
                const float4 gv = *reinterpret_cast<const float4*>(g + lq + q * 4);
                const float4 bv = *reinterpret_cast<const float4*>(beta + lq + q * 4);
                const float4 rr = *reinterpret_cast<const float4*>(grp + q * 4);
                float4 y;
                y.x = (v.x - mean) * rstd * gv.x + bv.x + rr.x;
                y.y = (v.y - mean) * rstd * gv.y + bv.y + rr.y;
                y.z = (v.z - mean) * rstd * gv.z + bv.z + rr.z;
                y.w = (v.w - mean) * rstd * gv.w + bv.w + rr.w;
                *reinterpret_cast<float4*>(op + q * 4) = y;
            }
        }
    }

    if (EDGE) {
        __syncthreads();
        // coalesced atomic scatter: each wave scatters 16 rows, lane-consecutive
#pragma unroll
        for (int r = 0; r < 16; ++r) {
            const int row = wave * 16 + r;
            const int dst = didx[row];
            float* ap = outp + (size_t)dst * 128;
            atomicAdd(ap + lane, outl[row * LDO + lane]);
            atomicAdd(ap + 64 + lane, outl[row * LDO + 64 + lane]);
        }
    }
}

extern "C" void kernel_launch(void* const* d_in, const int* in_sizes, int n_in,
                              void* d_out, int out_size, void* d_ws, size_t ws_size,
                              hipStream_t stream) {
    const float* m2g = (const float*)d_in[0];
    const float* gridf = (const float*)d_in[1];
    const float* meshf = (const float*)d_in[2];
    const int* src_idx = (const int*)d_in[3];
    const int* dst_idx = (const int*)d_in[4];
    const float* eW1 = (const float*)d_in[5];
    const float* eb1 = (const float*)d_in[6];
    const float* eW2 = (const float*)d_in[7];
    const float* eb2 = (const float*)d_in[8];
    const float* eg = (const float*)d_in[9];
    const float* ebeta = (const float*)d_in[10];
    const float* nW1 = (const float*)d_in[11];
    const float* nb1 = (const float*)d_in[12];
    const float* nW2 = (const float*)d_in[13];
    const float* nb2 = (const float*)d_in[14];
    const float* ng = (const float*)d_in[15];
    const float* nbeta = (const float*)d_in[16];
    float* out = (float*)d_out;

    const int mesh_elems = in_sizes[2];        // N_MESH * 128
    const int grid_elems = N_GRID * 128;

    bf16_t* W1eT = (bf16_t*)d_ws;              // [256][384]
    bf16_t* W2eT = W1eT + 256 * 384;           // [128][256]
    bf16_t* W1nT = W2eT + 128 * 256;           // [256][256]
    bf16_t* W2nT = W1nT + 256 * 256;           // [128][256]
    bf16_t* gridb = W2nT + 128 * 256;
    bf16_t* meshb = gridb + grid_elems;

    const size_t need = (size_t)(229376 + grid_elems + mesh_elems) * sizeof(bf16_t);
    const bool tbl = ws_size >= need;

    // agg lives in d_out; zero it first (edge kernel atomically accumulates into it)
    hipMemsetAsync(d_out, 0, (size_t)N_GRID * 128 * sizeof(float), stream);

    transpose_to_bf16<<<(384 * 256 + 255) / 256, 256, 0, stream>>>(eW1, W1eT, 384, 256);
    transpose_to_bf16<<<(256 * 128 + 255) / 256, 256, 0, stream>>>(eW2, W2eT, 256, 128);
    transpose_to_bf16<<<(256 * 256 + 255) / 256, 256, 0, stream>>>(nW1, W1nT, 256, 256);
    transpose_to_bf16<<<(256 * 128 + 255) / 256, 256, 0, stream>>>(nW2, W2nT, 256, 128);

    if (tbl) {
        const int g8 = grid_elems / 8, m8 = mesh_elems / 8;
        f32_to_bf16_vec<<<(g8 + 255) / 256, 256, 0, stream>>>(gridf, gridb, g8);
        f32_to_bf16_vec<<<(m8 + 255) / 256, 256, 0, stream>>>(meshf, meshb, m8);
        mlp_kernel<true, true><<<E_EDGE / 128, 512, 0, stream>>>(
            m2g, gridf, meshf, gridb, meshb, src_idx, dst_idx,
            W1eT, eb1, W2eT, eb2, eg, ebeta, out);
        mlp_kernel<false, true><<<N_GRID / 128, 512, 0, stream>>>(
            out, gridf, nullptr, gridb, nullptr, nullptr, nullptr,
            W1nT, nb1, W2nT, nb2, ng, nbeta, out);
    } else {
        mlp_kernel<true, false><<<E_EDGE / 128, 512, 0, stream>>>(
            m2g, gridf, meshf, nullptr, nullptr, src_idx, dst_idx,
            W1eT, eb1, W2eT, eb2, eg, ebeta, out);
        mlp_kernel<false, false><<<N_GRID / 128, 512, 0, stream>>>(
            out, gridf, nullptr, nullptr, nullptr, nullptr, nullptr,
            W1nT, nb1, W2nT, nb2, ng, nbeta, out);
    }
}

// Round 7
// 812.600 us; speedup vs baseline: 1.3960x; 1.0149x over previous
//
#include <hip/hip_runtime.h>
#include <hip/hip_bf16.h>

typedef __bf16 bf16_t;
typedef bf16_t bf16x8 __attribute__((ext_vector_type(8)));
typedef float f32x16 __attribute__((ext_vector_type(16)));

#define MFMA32(a, b, c) __builtin_amdgcn_mfma_f32_32x32x16_bf16(a, b, c, 0, 0, 0)

static constexpr int E_EDGE = 786432;
static constexpr int N_GRID = 262144;

// LDS geometry
static constexpr int LDT = 72;                  // A-tile row elems (64+8)
static constexpr int ATB = 128 * LDT * 2;       // 18432 B per A tile
static constexpr int LDH = 264;                 // h row elems (256+8)
static constexpr int LDO = 132;                 // out row f32 elems
static constexpr int HB = 128 * LDH * 2;        // 67584 B (== 128*LDO*4)
static constexpr int OFF_SIDX = HB;
static constexpr int OFF_DIDX = OFF_SIDX + 512;
static constexpr int SMEM_SZ = OFF_DIDX + 512;  // 68608 B -> 2 blocks/CU

// LDS-only barrier: does NOT drain vmcnt, so register-prefetch global loads
// stay in flight across it (the __syncthreads lowering drains vmcnt(0) and
// was serializing the gather pipeline). All cross-wave dependencies in the
// K-loop are LDS writes/reads -> lgkmcnt(0) + s_barrier is sufficient.
__device__ __forceinline__ void lds_barrier() {
    asm volatile("s_waitcnt lgkmcnt(0)" ::: "memory");
    __builtin_amdgcn_s_barrier();
    __builtin_amdgcn_sched_barrier(0);
}

// out[n*K + k] = (bf16) in[k*N + n]
__global__ void transpose_to_bf16(const float* __restrict__ in, bf16_t* __restrict__ out,
                                  int K, int N) {
    int idx = blockIdx.x * 256 + threadIdx.x;
    if (idx < K * N) {
        int n = idx / K;
        int k = idx - n * K;
        out[idx] = (bf16_t)in[k * N + n];
    }
}

// packed f32 -> bf16 (8 elems/thread)
__global__ void f32_to_bf16_vec(const float* __restrict__ in, bf16_t* __restrict__ out, int n8) {
    int i = blockIdx.x * 256 + threadIdx.x;
    if (i < n8) {
        const float4* p = reinterpret_cast<const float4*>(in + (size_t)i * 8);
        const float4 a = p[0], b = p[1];
        union { bf16_t h[8]; uint4 u; } pk;
        pk.h[0] = (bf16_t)a.x; pk.h[1] = (bf16_t)a.y; pk.h[2] = (bf16_t)a.z; pk.h[3] = (bf16_t)a.w;
        pk.h[4] = (bf16_t)b.x; pk.h[5] = (bf16_t)b.y; pk.h[6] = (bf16_t)b.z; pk.h[7] = (bf16_t)b.w;
        reinterpret_cast<uint4*>(out)[i] = pk.u;
    }
}

// Fused MLP: cat(...)[K1] -> 256 (SiLU) -> 128 (LN) -> scatter/store.
// BM=128 rows/block, 512 threads (8 waves).
// GEMM1: each wave owns one 32-wide N-slice over all 128 rows; B from L2
// (prefetched 1 step ahead). A gathered via 3-deep register prefetch, staged
// to dbuf LDS with lgkmcnt-only barriers (gathers stay in flight).
// GEMM2: waves 2M x 4N; W2 in registers, no staging barriers.
template <bool EDGE, bool TBL>
__global__ __launch_bounds__(512, 4) void mlp_kernel(
    const float* feat0,                 // EDGE: m2g_efeat ; NODE: agg (= out)
    const float* __restrict__ gridf,
    const float* __restrict__ meshf,
    const bf16_t* __restrict__ gridb,   // bf16 tables (TBL only)
    const bf16_t* __restrict__ meshb,
    const int* __restrict__ src_idx,
    const int* __restrict__ dst_idx,
    const bf16_t* __restrict__ W1T,     // [256][K1]
    const float* __restrict__ b1,
    const bf16_t* __restrict__ W2T,     // [128][256]
    const float* __restrict__ b2,
    const float* __restrict__ g, const float* __restrict__ beta,
    float* outp)                        // EDGE: agg (atomic) ; NODE: out
{
    __shared__ __align__(16) char smem[SMEM_SZ];

    constexpr int K1 = EDGE ? 384 : 256;
    constexpr int NSTEP = K1 / 64;

    const int tid = threadIdx.x;
    const int wave = tid >> 6, lane = tid & 63;
    const int l31 = lane & 31, lk = lane >> 5;
    const int wm = wave >> 2, wn = wave & 3;
    const int r0 = blockIdx.x * 128;

    int* sidx = (int*)(smem + OFF_SIDX);
    int* didx = (int*)(smem + OFF_DIDX);
    if (EDGE) {
        if (tid < 128) sidx[tid] = src_idx[r0 + tid];
        else if (tid < 256) didx[tid - 128] = dst_idx[r0 + tid - 128];
        lds_barrier();
    }

    // ---------------- GEMM1: [128,K1] x [K1,256] ----------------
    const int srow = tid >> 2;      // staging row 0..127
    const int sq = (tid & 3) * 16;  // 16-col chunk within K64 step

    union AReg { float4 f[4]; uint4 b[2]; };
    AReg R[3];
    bf16x8 bfr[2][4];

    auto LOADA = [&](int step, int set) {
        if (step < 2) {
            const float* base = feat0 + (size_t)(r0 + srow) * 128 + step * 64 + sq;
#pragma unroll
            for (int j = 0; j < 4; ++j)
                R[set].f[j] = *reinterpret_cast<const float4*>(base + j * 4);
        } else if (TBL) {
            const bf16_t* bp;
            if (EDGE)
                bp = (step < 4) ? meshb + (size_t)sidx[srow] * 128 + (step - 2) * 64 + sq
                                : gridb + (size_t)didx[srow] * 128 + (step - 4) * 64 + sq;
            else
                bp = gridb + (size_t)(r0 + srow) * 128 + (step - 2) * 64 + sq;
            R[set].b[0] = *reinterpret_cast<const uint4*>(bp);
            R[set].b[1] = *reinterpret_cast<const uint4*>(bp + 8);
        } else {
            const float* base;
            if (EDGE)
                base = (step < 4) ? meshf + (size_t)sidx[srow] * 128 + (step - 2) * 64 + sq
                                  : gridf + (size_t)didx[srow] * 128 + (step - 4) * 64 + sq;
            else
                base = gridf + (size_t)(r0 + srow) * 128 + (step - 2) * 64 + sq;
#pragma unroll
            for (int j = 0; j < 4; ++j)
                R[set].f[j] = *reinterpret_cast<const float4*>(base + j * 4);
        }
    };
    auto WRITEA = [&](int step, int set, int p) {
        bf16_t* dst = (bf16_t*)(smem + p * ATB) + srow * LDT + sq;
        if (step < 2 || !TBL) {
#pragma unroll
            for (int q = 0; q < 2; ++q) {
                union { bf16_t h[8]; uint4 u; } pk;
                const float4 v0 = R[set].f[q * 2], v1 = R[set].f[q * 2 + 1];
                pk.h[0] = (bf16_t)v0.x; pk.h[1] = (bf16_t)v0.y;
                pk.h[2] = (bf16_t)v0.z; pk.h[3] = (bf16_t)v0.w;
                pk.h[4] = (bf16_t)v1.x; pk.h[5] = (bf16_t)v1.y;
                pk.h[6] = (bf16_t)v1.z; pk.h[7] = (bf16_t)v1.w;
                *reinterpret_cast<uint4*>(dst + q * 8) = pk.u;
            }
        } else {
            *reinterpret_cast<uint4*>(dst) = R[set].b[0];
            *reinterpret_cast<uint4*>(dst + 8) = R[set].b[1];
        }
    };
    auto LOADB = [&](int step, int set) {
        const bf16_t* wrow = W1T + (size_t)(wave * 32 + l31) * K1 + step * 64 + lk * 8;
#pragma unroll
        for (int ks = 0; ks < 4; ++ks)
            bfr[set][ks] = *reinterpret_cast<const bf16x8*>(wrow + ks * 16);
    };

    f32x16 acc[4] = {};
    LOADA(0, 0);
    LOADA(1, 1);
    LOADA(2, 2);
    WRITEA(0, 0, 0);
    LOADB(0, 0);
    lds_barrier();
#pragma unroll
    for (int t = 0; t < NSTEP; ++t) {
        if (t + 3 < NSTEP) LOADA(t + 3, (t + 3) % 3);   // 3-deep gather prefetch
        if (t + 1 < NSTEP) {
            WRITEA(t + 1, (t + 1) % 3, (t + 1) & 1);    // stage next (other buffer)
            LOADB(t + 1, (t + 1) & 1);                  // prefetch next b-frags
        }
        const bf16_t* A = (const bf16_t*)(smem + (t & 1) * ATB);
#pragma unroll
        for (int ks = 0; ks < 4; ++ks) {
            const int kb = ks * 16 + lk * 8;
            bf16x8 a[4];
#pragma unroll
            for (int mt = 0; mt < 4; ++mt)
                a[mt] = *reinterpret_cast<const bf16x8*>(A + (mt * 32 + l31) * LDT + kb);
#pragma unroll
            for (int mt = 0; mt < 4; ++mt)
                acc[mt] = MFMA32(a[mt], bfr[t & 1][ks], acc[mt]);
        }
        if (t + 1 < NSTEP) lds_barrier();
    }
    lds_barrier();  // last-step A reads done before h overwrites dbuf region

    // ---------------- bias + SiLU -> h [128][LDH] bf16 ----------------
    bf16_t* hT = (bf16_t*)smem;
    {
        const int col = wave * 32 + l31;   // this wave's N-slice (0..255)
        const float bb = b1[col];
#pragma unroll
        for (int mt = 0; mt < 4; ++mt)
#pragma unroll
            for (int r = 0; r < 16; ++r) {
                const int row = mt * 32 + (r & 3) + 8 * (r >> 2) + 4 * lk;
                const float x = acc[mt][r] + bb;
                hT[row * LDH + col] = (bf16_t)(x / (1.f + __expf(-x)));
            }
    }
    lds_barrier();

    // ---------------- GEMM2: [128,256] x [256,128]; W2 in regs, no barriers ----------------
    bf16x8 b2f[16];
#pragma unroll
    for (int ks = 0; ks < 16; ++ks)
        b2f[ks] = *reinterpret_cast<const bf16x8*>(
            W2T + (size_t)(wn * 32 + l31) * 256 + ks * 16 + lk * 8);

    f32x16 acc2[2] = {};
#pragma unroll
    for (int ks = 0; ks < 16; ++ks) {
        const int kb = ks * 16 + lk * 8;
        bf16x8 a[2];
#pragma unroll
        for (int mt = 0; mt < 2; ++mt)
            a[mt] = *reinterpret_cast<const bf16x8*>(hT + (wm * 64 + mt * 32 + l31) * LDH + kb);
#pragma unroll
        for (int mt = 0; mt < 2; ++mt)
            acc2[mt] = MFMA32(a[mt], b2f[ks], acc2[mt]);
    }
    lds_barrier();  // h reads done before outl overwrites it

    // ---------------- bias -> outl [128][LDO] f32 ----------------
    float* outl = (float*)smem;
    {
        const int col = wn * 32 + l31;
        const float bb = b2[col];
#pragma unroll
        for (int mt = 0; mt < 2; ++mt)
#pragma unroll
            for (int r = 0; r < 16; ++r) {
                const int row = wm * 64 + mt * 32 + (r & 3) + 8 * (r >> 2) + 4 * lk;
                outl[row * LDO + col] = acc2[mt][r] + bb;
            }
    }
    lds_barrier();

    // ---------------- LayerNorm: 4 threads per row ----------------
    {
        const int lrow = tid >> 2, lq = (tid & 3) * 32;
        const float* rp = outl + lrow * LDO + lq;
        float s = 0.f, sq2 = 0.f;
#pragma unroll
        for (int q = 0; q < 8; ++q) {
            const float4 v = *reinterpret_cast<const float4*>(rp + q * 4);
            s += v.x + v.y + v.z + v.w;
            sq2 += v.x * v.x + v.y * v.y + v.z * v.z + v.w * v.w;
        }
        s += __shfl_xor(s, 1);  sq2 += __shfl_xor(sq2, 1);
        s += __shfl_xor(s, 2);  sq2 += __shfl_xor(sq2, 2);
        const float mean = s * (1.f / 128.f);
        const float var = sq2 * (1.f / 128.f) - mean * mean;
        const float rstd = rsqrtf(var + 1e-5f);

        if (EDGE) {
            float* wp = outl + lrow * LDO + lq;
#pragma unroll
            for (int q = 0; q < 8; ++q) {
                const float4 v = *reinterpret_cast<const float4*>(rp + q * 4);
                const float4 gv = *reinterpret_cast<const float4*>(g + lq + q * 4);
                const float4 bv = *reinterpret_cast<const float4*>(beta + lq + q * 4);
                float4 y;
                y.x = (v.x - mean) * rstd * gv.x + bv.x;
                y.y = (v.y - mean) * rstd * gv.y + bv.y;
                y.z = (v.z - mean) * rstd * gv.z + bv.z;
                y.w = (v.w - mean) * rstd * gv.w + bv.w;
                *reinterpret_cast<float4*>(wp + q * 4) = y;
            }
        } else {
            const float* grp = gridf + (size_t)(r0 + lrow) * 128 + lq;
            float* op = outp + (size_t)(r0 + lrow) * 128 + lq;
#pragma unroll
            for (int q = 0; q < 8; ++q) {
                const float4 v = *reinterpret_cast<const float4*>(rp + q * 4);
                const float4 gv = *reinterpret_cast<const float4*>(g + lq + q * 4);
                const float4 bv = *reinterpret_cast<const float4*>(beta + lq + q * 4);
                const float4 rr = *reinterpret_cast<const float4*>(grp + q * 4);
                float4 y;
                y.x = (v.x - mean) * rstd * gv.x + bv.x + rr.x;
                y.y = (v.y - mean) * rstd * gv.y + bv.y + rr.y;
                y.z = (v.z - mean) * rstd * gv.z + bv.z + rr.z;
                y.w = (v.w - mean) * rstd * gv.w + bv.w + rr.w;
                *reinterpret_cast<float4*>(op + q * 4) = y;
            }
        }
    }

    if (EDGE) {
        lds_barrier();
        // coalesced atomic scatter: each wave scatters 16 rows, lane-consecutive
#pragma unroll
        for (int r = 0; r < 16; ++r) {
            const int row = wave * 16 + r;
            const int dst = didx[row];
            float* ap = outp + (size_t)dst * 128;
            atomicAdd(ap + lane, outl[row * LDO + lane]);
            atomicAdd(ap + 64 + lane, outl[row * LDO + 64 + lane]);
        }
    }
}

extern "C" void kernel_launch(void* const* d_in, const int* in_sizes, int n_in,
                              void* d_out, int out_size, void* d_ws, size_t ws_size,
                              hipStream_t stream) {
    const float* m2g = (const float*)d_in[0];
    const float* gridf = (const float*)d_in[1];
    const float* meshf = (const float*)d_in[2];
    const int* src_idx = (const int*)d_in[3];
    const int* dst_idx = (const int*)d_in[4];
    const float* eW1 = (const float*)d_in[5];
    const float* eb1 = (const float*)d_in[6];
    const float* eW2 = (const float*)d_in[7];
    const float* eb2 = (const float*)d_in[8];
    const float* eg = (const float*)d_in[9];
    const float* ebeta = (const float*)d_in[10];
    const float* nW1 = (const float*)d_in[11];
    const float* nb1 = (const float*)d_in[12];
    const float* nW2 = (const float*)d_in[13];
    const float* nb2 = (const float*)d_in[14];
    const float* ng = (const float*)d_in[15];
    const float* nbeta = (const float*)d_in[16];
    float* out = (float*)d_out;

    const int mesh_elems = in_sizes[2];        // N_MESH * 128
    const int grid_elems = N_GRID * 128;

    bf16_t* W1eT = (bf16_t*)d_ws;              // [256][384]
    bf16_t* W2eT = W1eT + 256 * 384;           // [128][256]
    bf16_t* W1nT = W2eT + 128 * 256;           // [256][256]
    bf16_t* W2nT = W1nT + 256 * 256;           // [128][256]
    bf16_t* gridb = W2nT + 128 * 256;
    bf16_t* meshb = gridb + grid_elems;

    const size_t need = (size_t)(229376 + grid_elems + mesh_elems) * sizeof(bf16_t);
    const bool tbl = ws_size >= need;

    // agg lives in d_out; zero it first (edge kernel atomically accumulates into it)
    hipMemsetAsync(d_out, 0, (size_t)N_GRID * 128 * sizeof(float), stream);

    transpose_to_bf16<<<(384 * 256 + 255) / 256, 256, 0, stream>>>(eW1, W1eT, 384, 256);
    transpose_to_bf16<<<(256 * 128 + 255) / 256, 256, 0, stream>>>(eW2, W2eT, 256, 128);
    transpose_to_bf16<<<(256 * 256 + 255) / 256, 256, 0, stream>>>(nW1, W1nT, 256, 256);
    transpose_to_bf16<<<(256 * 128 + 255) / 256, 256, 0, stream>>>(nW2, W2nT, 256, 128);

    if (tbl) {
        const int g8 = grid_elems / 8, m8 = mesh_elems / 8;
        f32_to_bf16_vec<<<(g8 + 255) / 256, 256, 0, stream>>>(gridf, gridb, g8);
        f32_to_bf16_vec<<<(m8 + 255) / 256, 256, 0, stream>>>(meshf, meshb, m8);
        mlp_kernel<true, true><<<E_EDGE / 128, 512, 0, stream>>>(
            m2g, gridf, meshf, gridb, meshb, src_idx, dst_idx,
            W1eT, eb1, W2eT, eb2, eg, ebeta, out);
        mlp_kernel<false, true><<<N_GRID / 128, 512, 0, stream>>>(
            out, gridf, nullptr, gridb, nullptr, nullptr, nullptr,
            W1nT, nb1, W2nT, nb2, ng, nbeta, out);
    } else {
        mlp_kernel<true, false><<<E_EDGE / 128, 512, 0, stream>>>(
            m2g, gridf, meshf, nullptr, nullptr, src_idx, dst_idx,
            W1eT, eb1, W2eT, eb2, eg, ebeta, out);
        mlp_kernel<false, false><<<N_GRID / 128, 512, 0, stream>>>(
            out, gridf, nullptr, nullptr, nullptr, nullptr, nullptr,
            W1nT, nb1, W2nT, nb2, ng, nbeta, out);
    }
}

// Round 8
// 791.133 us; speedup vs baseline: 1.4339x; 1.0271x over previous
//
#include <hip/hip_runtime.h>
#include <hip/hip_bf16.h>

typedef __bf16 bf16_t;
typedef bf16_t bf16x8 __attribute__((ext_vector_type(8)));
typedef float f32x16 __attribute__((ext_vector_type(16)));

#define MFMA32(a, b, c) __builtin_amdgcn_mfma_f32_32x32x16_bf16(a, b, c, 0, 0, 0)

static constexpr int E_EDGE = 786432;
static constexpr int N_GRID = 262144;

// LDS geometry
static constexpr int LDT = 72;                  // A-tile row elems (64+8)
static constexpr int ATB = 128 * LDT * 2;       // 18432 B per A tile
static constexpr int LDH = 264;                 // h row elems (256+8)
static constexpr int LDO = 132;                 // out row f32 elems
static constexpr int HB = 128 * LDH * 2;        // 67584 B (== 128*LDO*4)
static constexpr int OFF_SIDX = HB;
static constexpr int OFF_DIDX = OFF_SIDX + 512;
static constexpr int OFF_SLOT = OFF_DIDX + 512;
static constexpr int SMEM_SZ = OFF_SLOT + 512;  // 69120 B -> 2 blocks/CU

// LDS-only barrier: does NOT drain vmcnt (global prefetches stay in flight).
__device__ __forceinline__ void lds_barrier() {
    asm volatile("s_waitcnt lgkmcnt(0)" ::: "memory");
    __builtin_amdgcn_s_barrier();
    __builtin_amdgcn_sched_barrier(0);
}

// out[n*K + k] = (bf16) in[k*N + n]
__global__ void transpose_to_bf16(const float* __restrict__ in, bf16_t* __restrict__ out,
                                  int K, int N) {
    int idx = blockIdx.x * 256 + threadIdx.x;
    if (idx < K * N) {
        int n = idx / K;
        int k = idx - n * K;
        out[idx] = (bf16_t)in[k * N + n];
    }
}

// packed f32 -> bf16 (8 elems/thread)
__global__ void f32_to_bf16_vec(const float* __restrict__ in, bf16_t* __restrict__ out, int n8) {
    int i = blockIdx.x * 256 + threadIdx.x;
    if (i < n8) {
        const float4* p = reinterpret_cast<const float4*>(in + (size_t)i * 8);
        const float4 a = p[0], b = p[1];
        union { bf16_t h[8]; uint4 u; } pk;
        pk.h[0] = (bf16_t)a.x; pk.h[1] = (bf16_t)a.y; pk.h[2] = (bf16_t)a.z; pk.h[3] = (bf16_t)a.w;
        pk.h[4] = (bf16_t)b.x; pk.h[5] = (bf16_t)b.y; pk.h[6] = (bf16_t)b.z; pk.h[7] = (bf16_t)b.w;
        reinterpret_cast<uint4*>(out)[i] = pk.u;
    }
}

// ---------------- CSR build ----------------
__global__ void k_hist(const int* __restrict__ dst, int* __restrict__ deg, int E) {
    int i = blockIdx.x * 256 + threadIdx.x;
    if (i < E) atomicAdd(&deg[dst[i]], 1);
}

// 256 blocks x 256 threads, 4 elems/thread: per-block exclusive scan + block sums
__global__ void k_scan1(const int* __restrict__ deg, int* __restrict__ excl,
                        int* __restrict__ bsum) {
    __shared__ int sd[256];
    const int b = blockIdx.x, t = threadIdx.x;
    int4 v = reinterpret_cast<const int4*>(deg)[b * 256 + t];
    const int s0 = v.x, s1 = s0 + v.y, s2 = s1 + v.z, s3 = s2 + v.w;
    sd[t] = s3;
    __syncthreads();
    for (int off = 1; off < 256; off <<= 1) {
        int val = (t >= off) ? sd[t - off] : 0;
        __syncthreads();
        if (t >= off) sd[t] += val;
        __syncthreads();
    }
    const int pre = (t > 0) ? sd[t - 1] : 0;
    int4 o;
    o.x = pre; o.y = pre + s0; o.z = pre + s1; o.w = pre + s2;
    reinterpret_cast<int4*>(excl)[b * 256 + t] = o;
    if (t == 255) bsum[b] = sd[255];
}

__global__ void k_scan2(const int* __restrict__ bsum, int* __restrict__ bofs) {
    __shared__ int sd[256];
    const int t = threadIdx.x;
    sd[t] = bsum[t];
    __syncthreads();
    for (int off = 1; off < 256; off <<= 1) {
        int val = (t >= off) ? sd[t - off] : 0;
        __syncthreads();
        if (t >= off) sd[t] += val;
        __syncthreads();
    }
    bofs[t] = (t > 0) ? sd[t - 1] : 0;
}

__global__ void k_scan3(const int* __restrict__ excl, const int* __restrict__ bofs,
                        int* __restrict__ rowptr, int* __restrict__ cursor, int N, int E) {
    int i = blockIdx.x * 256 + threadIdx.x;
    if (i < N) {
        const int v = excl[i] + bofs[i >> 10];
        rowptr[i] = v;
        cursor[i] = v;
    }
    if (i == 0) rowptr[N] = E;
}

__global__ void k_slot(const int* __restrict__ dst, int* __restrict__ cursor,
                       int* __restrict__ slot, int E) {
    int i = blockIdx.x * 256 + threadIdx.x;
    if (i < E) slot[i] = atomicAdd(&cursor[dst[i]], 1);
}

// Fused MLP: cat(...)[K1] -> 256 (SiLU) -> 128 (LN) -> store.
// MODE: 0 = plain f32 (no tables, atomic agg), 1 = bf16 tables + atomic agg (R7),
//       2 = CSR (EDGE writes bf16 rows to efs[slot]; NODE sums contiguous CSR
//           ranges of efs during A-staging; zero f32 atomics).
template <bool EDGE, int MODE>
__global__ __launch_bounds__(512, 4) void mlp_kernel(
    const float* feat0,                 // EDGE: m2g_efeat ; NODE(mode<2): agg (= out)
    const float* __restrict__ gridf,
    const float* __restrict__ meshf,
    const bf16_t* __restrict__ gridb,
    const bf16_t* __restrict__ meshb,
    const int* __restrict__ src_idx,
    const int* __restrict__ dst_idx,
    const int* __restrict__ aux,        // EDGE: slot_of_edge ; NODE: rowptr (mode 2)
    bf16_t* __restrict__ efs,           // sorted edge features (mode 2)
    const bf16_t* __restrict__ W1T,     // [256][K1]
    const float* __restrict__ b1,
    const bf16_t* __restrict__ W2T,     // [128][256]
    const float* __restrict__ b2,
    const float* __restrict__ g, const float* __restrict__ beta,
    float* outp)                        // EDGE(mode<2): agg atomic ; NODE: out
{
    __shared__ __align__(16) char smem[SMEM_SZ];

    constexpr bool TBL = MODE >= 1;
    constexpr bool CSR = MODE == 2;
    constexpr int K1 = EDGE ? 384 : 256;
    constexpr int NSTEP = K1 / 64;

    const int tid = threadIdx.x;
    const int wave = tid >> 6, lane = tid & 63;
    const int l31 = lane & 31, lk = lane >> 5;
    const int wm = wave >> 2, wn = wave & 3;
    const int r0 = blockIdx.x * 128;

    int* sidx = (int*)(smem + OFF_SIDX);
    int* didx = (int*)(smem + OFF_DIDX);
    int* slotl = (int*)(smem + OFF_SLOT);
    int* rp = sidx;  // NODE CSR: row bounds, 129 ints (spills 1 into didx region)

    if (EDGE) {
        if (tid < 128) sidx[tid] = src_idx[r0 + tid];
        else if (tid < 256) didx[tid - 128] = dst_idx[r0 + tid - 128];
        else if (CSR && tid < 384) slotl[tid - 256] = aux[r0 + tid - 256];
        lds_barrier();
    } else if (CSR) {
        if (tid < 129) rp[tid] = aux[r0 + tid];
        lds_barrier();
    }

    // ---------------- GEMM1: [128,K1] x [K1,256] ----------------
    const int srow = tid >> 2;      // staging row 0..127
    const int sq = (tid & 3) * 16;  // 16-col chunk within K64 step

    union AReg { float4 f[4]; uint4 b[2]; };
    AReg R[3];
    bf16x8 bfr[2][4];

    auto LOADA = [&](int step, int set) {
        if constexpr (CSR && !EDGE) {
            if (step < 2) {
                // aggregate: sum this node's contiguous CSR range of efs rows
                const int beg = rp[srow], end = rp[srow + 1];
                float s[16];
#pragma unroll
                for (int j = 0; j < 16; ++j) s[j] = 0.f;
                for (int e = beg; e < end; ++e) {
                    const bf16_t* p = efs + (size_t)e * 128 + step * 64 + sq;
                    bf16x8 h0 = *reinterpret_cast<const bf16x8*>(p);
                    bf16x8 h1 = *reinterpret_cast<const bf16x8*>(p + 8);
#pragma unroll
                    for (int j = 0; j < 8; ++j) {
                        s[j] += (float)h0[j];
                        s[8 + j] += (float)h1[j];
                    }
                }
                union { bf16_t h[16]; uint4 u[2]; } pk;
#pragma unroll
                for (int j = 0; j < 16; ++j) pk.h[j] = (bf16_t)s[j];
                R[set].b[0] = pk.u[0];
                R[set].b[1] = pk.u[1];
            } else {
                const bf16_t* bp = gridb + (size_t)(r0 + srow) * 128 + (step - 2) * 64 + sq;
                R[set].b[0] = *reinterpret_cast<const uint4*>(bp);
                R[set].b[1] = *reinterpret_cast<const uint4*>(bp + 8);
            }
            return;
        }
        if (step < 2) {
            const float* base = feat0 + (size_t)(r0 + srow) * 128 + step * 64 + sq;
#pragma unroll
            for (int j = 0; j < 4; ++j)
                R[set].f[j] = *reinterpret_cast<const float4*>(base + j * 4);
        } else if (TBL) {
            const bf16_t* bp;
            if (EDGE)
                bp = (step < 4) ? meshb + (size_t)sidx[srow] * 128 + (step - 2) * 64 + sq
                                : gridb + (size_t)didx[srow] * 128 + (step - 4) * 64 + sq;
            else
                bp = gridb + (size_t)(r0 + srow) * 128 + (step - 2) * 64 + sq;
            R[set].b[0] = *reinterpret_cast<const uint4*>(bp);
            R[set].b[1] = *reinterpret_cast<const uint4*>(bp + 8);
        } else {
            const float* base;
            if (EDGE)
                base = (step < 4) ? meshf + (size_t)sidx[srow] * 128 + (step - 2) * 64 + sq
                                  : gridf + (size_t)didx[srow] * 128 + (step - 4) * 64 + sq;
            else
                base = gridf + (size_t)(r0 + srow) * 128 + (step - 2) * 64 + sq;
#pragma unroll
            for (int j = 0; j < 4; ++j)
                R[set].f[j] = *reinterpret_cast<const float4*>(base + j * 4);
        }
    };
    auto WRITEA = [&](int step, int set, int p) {
        bf16_t* dst = (bf16_t*)(smem + p * ATB) + srow * LDT + sq;
        const bool f32src = (!TBL) || (step < 2 && (EDGE || !CSR));
        if (f32src) {
#pragma unroll
            for (int q = 0; q < 2; ++q) {
                union { bf16_t h[8]; uint4 u; } pk;
                const float4 v0 = R[set].f[q * 2], v1 = R[set].f[q * 2 + 1];
                pk.h[0] = (bf16_t)v0.x; pk.h[1] = (bf16_t)v0.y;
                pk.h[2] = (bf16_t)v0.z; pk.h[3] = (bf16_t)v0.w;
                pk.h[4] = (bf16_t)v1.x; pk.h[5] = (bf16_t)v1.y;
                pk.h[6] = (bf16_t)v1.z; pk.h[7] = (bf16_t)v1.w;
                *reinterpret_cast<uint4*>(dst + q * 8) = pk.u;
            }
        } else {
            *reinterpret_cast<uint4*>(dst) = R[set].b[0];
            *reinterpret_cast<uint4*>(dst + 8) = R[set].b[1];
        }
    };
    auto LOADB = [&](int step, int set) {
        const bf16_t* wrow = W1T + (size_t)(wave * 32 + l31) * K1 + step * 64 + lk * 8;
#pragma unroll
        for (int ks = 0; ks < 4; ++ks)
            bfr[set][ks] = *reinterpret_cast<const bf16x8*>(wrow + ks * 16);
    };

    f32x16 acc[4] = {};
    LOADA(0, 0);
    LOADA(1, 1);
    LOADA(2, 2);
    WRITEA(0, 0, 0);
    LOADB(0, 0);
    lds_barrier();
#pragma unroll
    for (int t = 0; t < NSTEP; ++t) {
        if (t + 3 < NSTEP) LOADA(t + 3, (t + 3) % 3);   // 3-deep gather prefetch
        if (t + 1 < NSTEP) {
            WRITEA(t + 1, (t + 1) % 3, (t + 1) & 1);    // stage next (other buffer)
            LOADB(t + 1, (t + 1) & 1);                  // prefetch next b-frags
        }
        const bf16_t* A = (const bf16_t*)(smem + (t & 1) * ATB);
#pragma unroll
        for (int ks = 0; ks < 4; ++ks) {
            const int kb = ks * 16 + lk * 8;
            bf16x8 a[4];
#pragma unroll
            for (int mt = 0; mt < 4; ++mt)
                a[mt] = *reinterpret_cast<const bf16x8*>(A + (mt * 32 + l31) * LDT + kb);
#pragma unroll
            for (int mt = 0; mt < 4; ++mt)
                acc[mt] = MFMA32(a[mt], bfr[t & 1][ks], acc[mt]);
        }
        if (t + 1 < NSTEP) lds_barrier();
    }
    lds_barrier();  // last-step A reads done before h overwrites dbuf region

    // ---------------- bias + SiLU -> h [128][LDH] bf16 ----------------
    bf16_t* hT = (bf16_t*)smem;
    {
        const int col = wave * 32 + l31;   // this wave's N-slice (0..255)
        const float bb = b1[col];
#pragma unroll
        for (int mt = 0; mt < 4; ++mt)
#pragma unroll
            for (int r = 0; r < 16; ++r) {
                const int row = mt * 32 + (r & 3) + 8 * (r >> 2) + 4 * lk;
                const float x = acc[mt][r] + bb;
                hT[row * LDH + col] = (bf16_t)(x / (1.f + __expf(-x)));
            }
    }
    lds_barrier();

    // ---------------- GEMM2: [128,256] x [256,128]; W2 in regs ----------------
    bf16x8 b2f[16];
#pragma unroll
    for (int ks = 0; ks < 16; ++ks)
        b2f[ks] = *reinterpret_cast<const bf16x8*>(
            W2T + (size_t)(wn * 32 + l31) * 256 + ks * 16 + lk * 8);

    f32x16 acc2[2] = {};
#pragma unroll
    for (int ks = 0; ks < 16; ++ks) {
        const int kb = ks * 16 + lk * 8;
        bf16x8 a[2];
#pragma unroll
        for (int mt = 0; mt < 2; ++mt)
            a[mt] = *reinterpret_cast<const bf16x8*>(hT + (wm * 64 + mt * 32 + l31) * LDH + kb);
#pragma unroll
        for (int mt = 0; mt < 2; ++mt)
            acc2[mt] = MFMA32(a[mt], b2f[ks], acc2[mt]);
    }
    lds_barrier();  // h reads done before outl overwrites it

    // ---------------- bias -> outl [128][LDO] f32 ----------------
    float* outl = (float*)smem;
    {
        const int col = wn * 32 + l31;
        const float bb = b2[col];
#pragma unroll
        for (int mt = 0; mt < 2; ++mt)
#pragma unroll
            for (int r = 0; r < 16; ++r) {
                const int row = wm * 64 + mt * 32 + (r & 3) + 8 * (r >> 2) + 4 * lk;
                outl[row * LDO + col] = acc2[mt][r] + bb;
            }
    }
    lds_barrier();

    // ---------------- LayerNorm: 4 threads per row ----------------
    {
        const int lrow = tid >> 2, lq = (tid & 3) * 32;
        const float* rpd = outl + lrow * LDO + lq;
        float s = 0.f, sq2 = 0.f;
#pragma unroll
        for (int q = 0; q < 8; ++q) {
            const float4 v = *reinterpret_cast<const float4*>(rpd + q * 4);
            s += v.x + v.y + v.z + v.w;
            sq2 += v.x * v.x + v.y * v.y + v.z * v.z + v.w * v.w;
        }
        s += __shfl_xor(s, 1);  sq2 += __shfl_xor(sq2, 1);
        s += __shfl_xor(s, 2);  sq2 += __shfl_xor(sq2, 2);
        const float mean = s * (1.f / 128.f);
        const float var = sq2 * (1.f / 128.f) - mean * mean;
        const float rstd = rsqrtf(var + 1e-5f);

        if (EDGE) {
            if constexpr (CSR) {
                // direct bf16 row store to efs[slot]
                const int sl = slotl[lrow];
                bf16_t* op = efs + (size_t)sl * 128 + lq;
                union { bf16_t h[32]; uint4 u[4]; } pk;
#pragma unroll
                for (int q = 0; q < 8; ++q) {
                    const float4 v = *reinterpret_cast<const float4*>(rpd + q * 4);
                    const float4 gv = *reinterpret_cast<const float4*>(g + lq + q * 4);
                    const float4 bv = *reinterpret_cast<const float4*>(beta + lq + q * 4);
                    pk.h[q * 4 + 0] = (bf16_t)((v.x - mean) * rstd * gv.x + bv.x);
                    pk.h[q * 4 + 1] = (bf16_t)((v.y - mean) * rstd * gv.y + bv.y);
                    pk.h[q * 4 + 2] = (bf16_t)((v.z - mean) * rstd * gv.z + bv.z);
                    pk.h[q * 4 + 3] = (bf16_t)((v.w - mean) * rstd * gv.w + bv.w);
                }
#pragma unroll
                for (int j = 0; j < 4; ++j)
                    *reinterpret_cast<uint4*>(op + j * 8) = pk.u[j];
            } else {
                float* wp = outl + lrow * LDO + lq;
#pragma unroll
                for (int q = 0; q < 8; ++q) {
                    const float4 v = *reinterpret_cast<const float4*>(rpd + q * 4);
                    const float4 gv = *reinterpret_cast<const float4*>(g + lq + q * 4);
                    const float4 bv = *reinterpret_cast<const float4*>(beta + lq + q * 4);
                    float4 y;
                    y.x = (v.x - mean) * rstd * gv.x + bv.x;
                    y.y = (v.y - mean) * rstd * gv.y + bv.y;
                    y.z = (v.z - mean) * rstd * gv.z + bv.z;
                    y.w = (v.w - mean) * rstd * gv.w + bv.w;
                    *reinterpret_cast<float4*>(wp + q * 4) = y;
                }
            }
        } else {
            const float* grp = gridf + (size_t)(r0 + lrow) * 128 + lq;
            float* op = outp + (size_t)(r0 + lrow) * 128 + lq;
#pragma unroll
            for (int q = 0; q < 8; ++q) {
                const float4 v = *reinterpret_cast<const float4*>(rpd + q * 4);
                const float4 gv = *reinterpret_cast<const float4*>(g + lq + q * 4);
                const float4 bv = *reinterpret_cast<const float4*>(beta + lq + q * 4);
                const float4 rr = *reinterpret_cast<const float4*>(grp + q * 4);
                float4 y;
                y.x = (v.x - mean) * rstd * gv.x + bv.x + rr.x;
                y.y = (v.y - mean) * rstd * gv.y + bv.y + rr.y;
                y.z = (v.z - mean) * rstd * gv.z + bv.z + rr.z;
                y.w = (v.w - mean) * rstd * gv.w + bv.w + rr.w;
                *reinterpret_cast<float4*>(op + q * 4) = y;
            }
        }
    }

    if (EDGE && !CSR) {
        lds_barrier();
        // coalesced atomic scatter: each wave scatters 16 rows, lane-consecutive
#pragma unroll
        for (int r = 0; r < 16; ++r) {
            const int row = wave * 16 + r;
            const int dst = didx[row];
            float* ap = outp + (size_t)dst * 128;
            atomicAdd(ap + lane, outl[row * LDO + lane]);
            atomicAdd(ap + 64 + lane, outl[row * LDO + 64 + lane]);
        }
    }
}

extern "C" void kernel_launch(void* const* d_in, const int* in_sizes, int n_in,
                              void* d_out, int out_size, void* d_ws, size_t ws_size,
                              hipStream_t stream) {
    const float* m2g = (const float*)d_in[0];
    const float* gridf = (const float*)d_in[1];
    const float* meshf = (const float*)d_in[2];
    const int* src_idx = (const int*)d_in[3];
    const int* dst_idx = (const int*)d_in[4];
    const float* eW1 = (const float*)d_in[5];
    const float* eb1 = (const float*)d_in[6];
    const float* eW2 = (const float*)d_in[7];
    const float* eb2 = (const float*)d_in[8];
    const float* eg = (const float*)d_in[9];
    const float* ebeta = (const float*)d_in[10];
    const float* nW1 = (const float*)d_in[11];
    const float* nb1 = (const float*)d_in[12];
    const float* nW2 = (const float*)d_in[13];
    const float* nb2 = (const float*)d_in[14];
    const float* ng = (const float*)d_in[15];
    const float* nbeta = (const float*)d_in[16];
    float* out = (float*)d_out;

    const size_t mesh_elems = (size_t)in_sizes[2];   // N_MESH * 128
    const size_t grid_elems = (size_t)N_GRID * 128;
    const size_t efs_elems = (size_t)E_EDGE * 128;

    char* base = (char*)d_ws;
    size_t off = 0;
    auto alloc = [&](size_t bytes) { size_t o = off; off = (off + bytes + 15) & ~(size_t)15; return o; };

    const size_t o_w1e = alloc(256 * 384 * 2);
    const size_t o_w2e = alloc(128 * 256 * 2);
    const size_t o_w1n = alloc(256 * 256 * 2);
    const size_t o_w2n = alloc(128 * 256 * 2);
    const size_t o_gridb = alloc(grid_elems * 2);
    const size_t o_meshb = alloc(mesh_elems * 2);
    const size_t need_tbl = off;
    const size_t o_efs = alloc(efs_elems * 2);
    const size_t o_rowptr = alloc((N_GRID + 1) * 4);
    const size_t o_cursor = alloc((size_t)N_GRID * 4);
    const size_t o_slot = alloc((size_t)E_EDGE * 4);
    const size_t o_deg = alloc((size_t)N_GRID * 4);
    const size_t o_excl = alloc((size_t)N_GRID * 4);
    const size_t o_bsum = alloc(256 * 4);
    const size_t o_bofs = alloc(256 * 4);
    const size_t need_csr = off;

    bf16_t* W1eT = (bf16_t*)(base + o_w1e);
    bf16_t* W2eT = (bf16_t*)(base + o_w2e);
    bf16_t* W1nT = (bf16_t*)(base + o_w1n);
    bf16_t* W2nT = (bf16_t*)(base + o_w2n);
    bf16_t* gridb = (bf16_t*)(base + o_gridb);
    bf16_t* meshb = (bf16_t*)(base + o_meshb);
    bf16_t* efs = (bf16_t*)(base + o_efs);
    int* rowptr = (int*)(base + o_rowptr);
    int* cursor = (int*)(base + o_cursor);
    int* slot = (int*)(base + o_slot);
    int* deg = (int*)(base + o_deg);
    int* excl = (int*)(base + o_excl);
    int* bsum = (int*)(base + o_bsum);
    int* bofs = (int*)(base + o_bofs);

    const bool csr = ws_size >= need_csr;
    const bool tbl = ws_size >= need_tbl;

    transpose_to_bf16<<<(384 * 256 + 255) / 256, 256, 0, stream>>>(eW1, W1eT, 384, 256);
    transpose_to_bf16<<<(256 * 128 + 255) / 256, 256, 0, stream>>>(eW2, W2eT, 256, 128);
    transpose_to_bf16<<<(256 * 256 + 255) / 256, 256, 0, stream>>>(nW1, W1nT, 256, 256);
    transpose_to_bf16<<<(256 * 128 + 255) / 256, 256, 0, stream>>>(nW2, W2nT, 256, 128);

    if (csr) {
        const int g8 = (int)(grid_elems / 8), m8 = (int)(mesh_elems / 8);
        f32_to_bf16_vec<<<(g8 + 255) / 256, 256, 0, stream>>>(gridf, gridb, g8);
        f32_to_bf16_vec<<<(m8 + 255) / 256, 256, 0, stream>>>(meshf, meshb, m8);
        // CSR build
        hipMemsetAsync(deg, 0, (size_t)N_GRID * 4, stream);
        k_hist<<<(E_EDGE + 255) / 256, 256, 0, stream>>>(dst_idx, deg, E_EDGE);
        k_scan1<<<256, 256, 0, stream>>>(deg, excl, bsum);
        k_scan2<<<1, 256, 0, stream>>>(bsum, bofs);
        k_scan3<<<(N_GRID + 255) / 256, 256, 0, stream>>>(excl, bofs, rowptr, cursor, N_GRID, E_EDGE);
        k_slot<<<(E_EDGE + 255) / 256, 256, 0, stream>>>(dst_idx, cursor, slot, E_EDGE);
        // fused MLPs, no f32 atomics anywhere
        mlp_kernel<true, 2><<<E_EDGE / 128, 512, 0, stream>>>(
            m2g, gridf, meshf, gridb, meshb, src_idx, dst_idx, slot, efs,
            W1eT, eb1, W2eT, eb2, eg, ebeta, out);
        mlp_kernel<false, 2><<<N_GRID / 128, 512, 0, stream>>>(
            nullptr, gridf, nullptr, gridb, nullptr, nullptr, nullptr, rowptr, efs,
            W1nT, nb1, W2nT, nb2, ng, nbeta, out);
    } else if (tbl) {
        const int g8 = (int)(grid_elems / 8), m8 = (int)(mesh_elems / 8);
        f32_to_bf16_vec<<<(g8 + 255) / 256, 256, 0, stream>>>(gridf, gridb, g8);
        f32_to_bf16_vec<<<(m8 + 255) / 256, 256, 0, stream>>>(meshf, meshb, m8);
        hipMemsetAsync(d_out, 0, (size_t)N_GRID * 128 * sizeof(float), stream);
        mlp_kernel<true, 1><<<E_EDGE / 128, 512, 0, stream>>>(
            m2g, gridf, meshf, gridb, meshb, src_idx, dst_idx, nullptr, nullptr,
            W1eT, eb1, W2eT, eb2, eg, ebeta, out);
        mlp_kernel<false, 1><<<N_GRID / 128, 512, 0, stream>>>(
            out, gridf, nullptr, gridb, nullptr, nullptr, nullptr, nullptr, nullptr,
            W1nT, nb1, W2nT, nb2, ng, nbeta, out);
    } else {
        hipMemsetAsync(d_out, 0, (size_t)N_GRID * 128 * sizeof(float), stream);
        mlp_kernel<true, 0><<<E_EDGE / 128, 512, 0, stream>>>(
            m2g, gridf, meshf, nullptr, nullptr, src_idx, dst_idx, nullptr, nullptr,
            W1eT, eb1, W2eT, eb2, eg, ebeta, out);
        mlp_kernel<false, 0><<<N_GRID / 128, 512, 0, stream>>>(
            out, gridf, nullptr, nullptr, nullptr, nullptr, nullptr, nullptr, nullptr,
            W1nT, nb1, W2nT, nb2, ng, nbeta, out);
    }
}